// Round 8
// baseline (103.663 us; speedup 1.0000x reference)
//
#include <hip/hip_runtime.h>
#include <hip/hip_bf16.h>

#define NN    4096
#define KNEI  16
#define QPW   4              // query nodes per wave
#define WPB   16             // waves per block
#define BLOCK (WPB * 64)
#define QPB   (WPB * QPW)    // 64 queries per block
#define BIGF  3.0e38f

typedef float f32x2 __attribute__((ext_vector_type(2)));

// ---------------- DPP wave reductions (VALU pipe, no LDS) ----------------
// row_shr:n = 0x110|n ; row_bcast15 = 0x142 ; row_bcast31 = 0x143

__device__ __forceinline__ float wave_max_dpp(float v)   // lane 63 -> wave max
{
    float f = v;
#define STEPX(CTRL)                                                          \
    { int s_ = __builtin_amdgcn_update_dpp(__float_as_int(f),                \
               __float_as_int(f), (CTRL), 0xF, 0xF, false);                  \
      f = fmaxf(f, __int_as_float(s_)); }
    STEPX(0x111) STEPX(0x112) STEPX(0x114) STEPX(0x118) STEPX(0x142) STEPX(0x143)
#undef STEPX
    return f;
}

__device__ __forceinline__ int wave_min_i32_dpp(int v)   // lane 63 -> wave min
{
    int f = v;
#define STEPM(CTRL)                                                          \
    { int s_ = __builtin_amdgcn_update_dpp(f, f, (CTRL), 0xF, 0xF, false);   \
      f = min(f, s_); }
    STEPM(0x111) STEPM(0x112) STEPM(0x114) STEPM(0x118) STEPM(0x142) STEPM(0x143)
#undef STEPM
    return f;
}

__device__ __forceinline__ float row16_sum_dpp(float v)  // lane 16r+15 -> row sum
{
    float f = v;
#define STEPA(CTRL)                                                          \
    { int s_ = __builtin_amdgcn_update_dpp(0, __float_as_int(f),             \
               (CTRL), 0xF, 0xF, true);                                      \
      f += __int_as_float(s_); }
    STEPA(0x111) STEPA(0x112) STEPA(0x114) STEPA(0x118)
#undef STEPA
    return f;
}

// surrogate score: larger == closer.  pts[j] = (x, y, z, -n2/2)
__device__ __forceinline__ float score_calc(const float4 P, float xi, float yi,
                                            float zi, int j, int iLoc)
{
    float s = fmaf(P.x, xi, fmaf(P.y, yi, fmaf(P.z, zi, P.w)));
    return (j == iLoc) ? -1.0e30f : s;
}

// Branchless wave argmax; ties -> lowest idx (stable top_k). All candidates
// with index j live in lane (j & 63), so the owner lane is midx & 63.
__device__ __forceinline__ void argmax_bl(float v, int idx, float& M, int& midx)
{
    float f = wave_max_dpp(v);
    M = __int_as_float(__builtin_amdgcn_readlane(__float_as_int(f), 63));
    int ci = (v == M) ? idx : 0x7fffffff;
    ci = wave_min_i32_dpp(ci);
    midx = __builtin_amdgcn_readlane(ci, 63);
}

// Rescan lane w's 64-candidate column, refill its top-2 unused candidates.
__device__ __forceinline__ void replay_fill(const float4* __restrict__ pts, int w,
    float xq, float yq, float zq, int qLoc, unsigned long long usedw, int lane,
    float& b, int& bi, float& s, int& si)
{
    int j2 = w + (lane << 6);
    float scr = score_calc(pts[j2], xq, yq, zq, j2, qLoc);
    if ((usedw >> lane) & 1ull) scr = -BIGF;
    float M1; int i1;
    argmax_bl(scr, j2, M1, i1);
    if (j2 == i1) scr = -BIGF;            // drop the max, find the second
    float M2; int i2;
    argmax_bl(scr, j2, M2, i2);
    if (lane == w) { b = M1; bi = i1; s = M2; si = i2; }
}

// s_new = median(d, s_old, b_old); strict-> keeps stable ordering on ties
#define LADDER(d, b, bi, s, si)                                   \
    {  bool gtb = (d) > (b); bool gts = (d) > (s);                \
       (s)  = __builtin_amdgcn_fmed3f((d), (s), (b));             \
       (si) = gtb ? (bi) : (gts ? j : (si));                      \
       (b)  = fmaxf((b), (d));                                    \
       (bi) = gtb ? j : (bi); }

// one extraction round for query q (branchless; replay deferred via needMask)
#define ROUND(q, b, bi, s, si, used, wq)                                     \
    {   float M_; int mi_;                                                   \
        argmax_bl((b), (bi), M_, mi_);                                       \
        wq = mi_ & 63;                                                       \
        if (lane == ((q) << 4) + r) selIdx = mi_;                            \
        int sW_ = __builtin_amdgcn_readlane((si), wq);                       \
        if (lane == wq) {                                                    \
            (used) |= 1ull << ((unsigned)((bi) >> 6) & 63u);                 \
            (b) = (s); (bi) = (si); (s) = -BIGF; (si) = -1;                  \
        }                                                                    \
        needMask |= (sW_ == -1) ? (1u << (q)) : 0u;                          \
    }

#define DO_REPLAY(q, b, bi, s, si, used, wq, xq, yq, zq)                     \
    if (needMask & (1u << (q))) {                                            \
        unsigned lo_ = (unsigned)__builtin_amdgcn_readlane(                  \
                           (int)((used) & 0xffffffffull), wq);               \
        unsigned hi_ = (unsigned)__builtin_amdgcn_readlane(                  \
                           (int)((used) >> 32), wq);                         \
        replay_fill(pts, wq, xq, yq, zq, q0 + (q),                           \
                    ((unsigned long long)hi_ << 32) | lo_, lane,             \
                    b, bi, s, si);                                           \
    }

__global__ __launch_bounds__(BLOCK, 8)
void protein_enc_kernel(const float* __restrict__ coords,
                        const int*   __restrict__ atypes,
                        const int*   __restrict__ rtypes,
                        const float* __restrict__ tpw,
                        const float* __restrict__ aemb,
                        const float* __restrict__ remb,
                        float* __restrict__ out)
{
    __shared__ float4 pts[NN];      // x, y, z, -n2/2
    __shared__ float  sW[8 * 32];

    const int tid  = threadIdx.x;
    const int lane = tid & 63;
    const int wv   = tid >> 6;
    const int bpb  = NN / QPB;
    const int batch    = blockIdx.x / bpb;
    const int nodeBase = (blockIdx.x % bpb) * QPB;

    const float* cb = coords + (size_t)batch * NN * 3;

    // ---- staging: contiguous writes across lanes -> conflict-free ----
    for (int p = tid; p < NN; p += BLOCK) {
        float x = cb[3*p], y = cb[3*p+1], z = cb[3*p+2];
        pts[p] = make_float4(x, y, z, -0.5f * (x*x + y*y + z*z));
    }
    if (tid < 256) sW[tid] = tpw[tid];
    __syncthreads();

    const int q0 = nodeBase + wv * QPW;          // this wave's 4 query nodes
    const float4 P0 = pts[q0],   P1 = pts[q0+1];
    const float4 P2 = pts[q0+2], P3 = pts[q0+3];
    const float x0 = P0.x, y0 = P0.y, z0 = P0.z;
    const float x1 = P1.x, y1 = P1.y, z1 = P1.z;
    const float x2 = P2.x, y2 = P2.y, z2 = P2.z;
    const float x3 = P3.x, y3 = P3.y, z3 = P3.z;

    const f32x2 qAx = {x0, x1}, qAy = {y0, y1}, qAz = {z0, z1};
    const f32x2 qBx = {x2, x3}, qBy = {y2, y3}, qBz = {z2, z3};

    // ---- phase 1: 4 branchless per-lane top-2 ladders, one LDS read ----
    float b0 = -BIGF, s0 = -BIGF, b1 = -BIGF, s1 = -BIGF;
    float b2 = -BIGF, s2 = -BIGF, b3 = -BIGF, s3 = -BIGF;
    int bi0 = -1, si0 = -1, bi1 = -1, si1 = -1;
    int bi2 = -1, si2 = -1, bi3 = -1, si3 = -1;

    #pragma unroll 4
    for (int c = 0; c < NN / 64; ++c) {
        int j = lane + (c << 6);
        float4 P = pts[j];
        f32x2 Px = {P.x, P.x}, Py = {P.y, P.y}, Pz = {P.z, P.z}, Pw = {P.w, P.w};
        f32x2 dA = __builtin_elementwise_fma(Px, qAx,
                   __builtin_elementwise_fma(Py, qAy,
                   __builtin_elementwise_fma(Pz, qAz, Pw)));
        f32x2 dB = __builtin_elementwise_fma(Px, qBx,
                   __builtin_elementwise_fma(Py, qBy,
                   __builtin_elementwise_fma(Pz, qBz, Pw)));
        float d0 = dA.x, d1 = dA.y, d2 = dB.x, d3 = dB.y;
        LADDER(d0, b0, bi0, s0, si0)
        LADDER(d1, b1, bi1, s1, si1)
        LADDER(d2, b2, bi2, s2, si2)
        LADDER(d3, b3, bi3, s3, si3)
    }

    // self wins its own column: demote it (per query)
    if (lane == ((q0  ) & 63) && bi0 == q0  ) { b0 = s0; bi0 = si0; s0 = -BIGF; si0 = -1; }
    if (lane == ((q0+1) & 63) && bi1 == q0+1) { b1 = s1; bi1 = si1; s1 = -BIGF; si1 = -1; }
    if (lane == ((q0+2) & 63) && bi2 == q0+2) { b2 = s2; bi2 = si2; s2 = -BIGF; si2 = -1; }
    if (lane == ((q0+3) & 63) && bi3 == q0+3) { b3 = s3; bi3 = si3; s3 = -BIGF; si3 = -1; }

    // ---- phase 2: 16 rounds x 4 interleaved branchless extractions ----
    unsigned long long used0 = 0ull, used1 = 0ull, used2 = 0ull, used3 = 0ull;
    int selIdx = 0;                     // lane 16*q + r owns edge r of query q

    #pragma unroll 1
    for (int r = 0; r < KNEI; ++r) {
        unsigned needMask = 0u;
        int w0, w1, w2, w3;
        ROUND(0, b0, bi0, s0, si0, used0, w0)
        ROUND(1, b1, bi1, s1, si1, used1, w1)
        ROUND(2, b2, bi2, s2, si2, used2, w2)
        ROUND(3, b3, bi3, s3, si3, used3, w3)
        if (needMask) {                 // uniform, moderately rare
            DO_REPLAY(0, b0, bi0, s0, si0, used0, w0, x0, y0, z0)
            DO_REPLAY(1, b1, bi1, s1, si1, used1, w1, x1, y1, z1)
            DO_REPLAY(2, b2, bi2, s2, si2, used2, w2, x2, y2, z2)
            DO_REPLAY(3, b3, bi3, s3, si3, used3, w3, x3, y3, z3)
        }
    }

    // ---- epilogue: each lane computes its edge's 24 S-components once ----
    const int eq = lane >> 4;
    float xq = (eq & 2) ? ((eq & 1) ? x3 : x2) : ((eq & 1) ? x1 : x0);
    float yq = (eq & 2) ? ((eq & 1) ? y3 : y2) : ((eq & 1) ? y1 : y0);
    float zq = (eq & 2) ? ((eq & 1) ? z3 : z2) : ((eq & 1) ? z1 : z0);

    float4 P = pts[selIdx];
    float rx = P.x - xq, ry = P.y - yq, rz = P.z - zq;   // sender - receiver
    float dist = sqrtf(rx*rx + ry*ry + rz*rz);
    float inv  = 1.0f / (dist + 1e-8f);
    float hx = rx * inv, hy = ry * inv, hz = rz * inv;
    float cu = fminf(dist / 10.0f, 1.0f);
    float gg[8], ssum = 0.0f;
    #pragma unroll
    for (int v = 0; v < 8; ++v) {
        float d = cu - (float)v * (1.0f / 7.0f);
        gg[v] = expf(d * d * -32.0f);
        ssum += gg[v];
    }
    float is = 1.0f / ssum;
    float S[24];
    #pragma unroll
    for (int v = 0; v < 8; ++v) {
        float rbv = gg[v] * is;
        S[3*v]   = rbv * hx;
        S[3*v+1] = rbv * hy;
        S[3*v+2] = rbv * hz;
    }
    // sum the 16 edges within each query's 16-lane row (DPP, VALU-only)
    #pragma unroll
    for (int t = 0; t < 24; ++t) S[t] = row16_sum_dpp(S[t]);

    // W column held once in registers, reused for all 4 queries
    float wcol[8];
    #pragma unroll
    for (int v = 0; v < 8; ++v) wcol[v] = sW[32*v + (lane & 31)];

    const float scale = 0.036084391824351613f;   // 1/(16*sqrt(3))
    const float4 z4 = make_float4(0.f, 0.f, 0.f, 0.f);

    #pragma unroll
    for (int q = 0; q < QPW; ++q) {
        const int gq = batch * NN + q0 + q;
        float sg[24];
        #pragma unroll
        for (int t = 0; t < 24; ++t)
            sg[t] = __int_as_float(
                __builtin_amdgcn_readlane(__float_as_int(S[t]), 16 * q + 15));

        float* onode = out + (size_t)gq * 464;
        float4* o4 = (float4*)onode;
        if (lane < 16)       o4[lane] = z4;          // ch 0..63
        else if (lane < 36)  o4[lane + 24] = z4;     // ch 160..239

        if (lane < 32) {
            float a0 = 0.f, a1 = 0.f, a2 = 0.f;
            #pragma unroll
            for (int v = 0; v < 8; ++v) {
                a0 = fmaf(wcol[v], sg[3*v],   a0);
                a1 = fmaf(wcol[v], sg[3*v+1], a1);
                a2 = fmaf(wcol[v], sg[3*v+2], a2);
            }
            onode[64 + 3*lane]     = a0 * scale;
            onode[64 + 3*lane + 1] = a1 * scale;
            onode[64 + 3*lane + 2] = a2 * scale;
        }

        const int at = atypes[gq];
        const int rt = rtypes[gq];
        if (lane < 56) {
            float4 v = (lane < 28)
                ? ((const float4*)(aemb + 112*at))[lane]
                : ((const float4*)(remb + 112*rt))[lane - 28];
            o4[60 + lane] = v;
        }
    }
}

extern "C" void kernel_launch(void* const* d_in, const int* in_sizes, int n_in,
                              void* d_out, int out_size, void* d_ws, size_t ws_size,
                              hipStream_t stream)
{
    const float* coords = (const float*)d_in[0];
    const int*   at     = (const int*)  d_in[1];
    const int*   rt     = (const int*)  d_in[2];
    const float* tpw    = (const float*)d_in[3];
    const float* ae     = (const float*)d_in[4];
    const float* re     = (const float*)d_in[5];
    float* out = (float*)d_out;

    const int B = in_sizes[1] / NN;                  // 8
    dim3 grid(B * (NN / QPB));
    protein_enc_kernel<<<grid, BLOCK, 0, stream>>>(coords, at, rt, tpw, ae, re, out);
}

// Round 10
// 90.739 us; speedup vs baseline: 1.1424x; 1.1424x over previous
//
#include <hip/hip_runtime.h>
#include <hip/hip_bf16.h>

#define NN    4096
#define KNEI  16
#define QPW   4              // query nodes per wave
#define WPB   16             // waves per block
#define BLOCK (WPB * 64)
#define QPB   (WPB * QPW)    // 64 queries per block
#define BIGF  3.0e38f

typedef float f32x2 __attribute__((ext_vector_type(2)));

// ---------------- DPP wave reductions (VALU pipe, no LDS) ----------------
template<int CTRL>
__device__ __forceinline__ float dppmax_step(float f)
{
    int s_ = __builtin_amdgcn_update_dpp(__float_as_int(f), __float_as_int(f),
                                         CTRL, 0xF, 0xF, false);
    return fmaxf(f, __int_as_float(s_));
}

__device__ __forceinline__ float wave_max_dpp(float v)   // lane 63 -> wave max
{
    float f = v;
    f = dppmax_step<0x111>(f); f = dppmax_step<0x112>(f);
    f = dppmax_step<0x114>(f); f = dppmax_step<0x118>(f);
    f = dppmax_step<0x142>(f); f = dppmax_step<0x143>(f);
    return f;
}

__device__ __forceinline__ float row16_sum_dpp(float v)  // lane 16r+15 -> row sum
{
    float f = v;
#define STEPA(CTRL)                                                          \
    { int s_ = __builtin_amdgcn_update_dpp(0, __float_as_int(f),             \
               (CTRL), 0xF, 0xF, true);                                      \
      f += __int_as_float(s_); }
    STEPA(0x111) STEPA(0x112) STEPA(0x114) STEPA(0x118)
#undef STEPA
    return f;
}

__device__ __forceinline__ int rlane(int v, int l)
{ return __builtin_amdgcn_readlane(v, l); }
__device__ __forceinline__ float rlanef(float v, int l)
{ return __int_as_float(__builtin_amdgcn_readlane(__float_as_int(v), l)); }

// lite argmax: winner = lowest LANE holding the max (no index tie-break;
// only the top-16 SET feeds a sum, so order/tie choice is output-neutral)
__device__ __forceinline__ void argmax_lite(float v, int idx,
                                            float& M, int& mi, int& w)
{
    M = rlanef(wave_max_dpp(v), 63);
    unsigned long long k = __ballot(v == M);
    w = __ffsll(k) - 1;
    mi = rlane(idx, w);
}

// Rescan owner w's 64-candidate column (diagonal map), refill top-2 unused.
__device__ __forceinline__ void replay_fill(const float4* __restrict__ pts, int w,
    float xq, float yq, float zq, int qLoc, unsigned long long usedw, int lane,
    float& b, int& bi, float& s, int& si)
{
    int j2 = (lane << 6) | (w ^ lane);        // slot t=lane of column w
    float4 P = pts[j2];
    float scr = fmaf(P.x, xq, fmaf(P.y, yq, fmaf(P.z, zq, P.w)));
    if (j2 == qLoc) scr = -BIGF;
    if ((usedw >> lane) & 1ull) scr = -BIGF;
    float M1; int i1, w1;
    argmax_lite(scr, j2, M1, i1, w1);
    if (lane == w1) scr = -BIGF;              // remove winner, find second
    float M2; int i2, w2;
    argmax_lite(scr, j2, M2, i2, w2);
    if (lane == w) { b = M1; bi = i1; s = M2; si = i2; }
}

// s_new = median(d, s_old, b_old); strict > keeps first-seen on ties
#define LADDER(d, b, bi, s, si)                                   \
    {  bool gtb = (d) > (b); bool gts = (d) > (s);                \
       (s)  = __builtin_amdgcn_fmed3f((d), (s), (b));             \
       (si) = gtb ? (bi) : (gts ? j : (si));                      \
       (b)  = fmaxf((b), (d));                                    \
       (bi) = gtb ? j : (bi); }

__global__ __launch_bounds__(BLOCK, 8)
void protein_enc_kernel(const float* __restrict__ coords,
                        const int*   __restrict__ atypes,
                        const int*   __restrict__ rtypes,
                        const float* __restrict__ tpw,
                        const float* __restrict__ aemb,
                        const float* __restrict__ remb,
                        float* __restrict__ out)
{
    __shared__ float4 pts[NN];      // x, y, z, -n2/2
    __shared__ float  sW[8 * 32];

    const int tid  = threadIdx.x;
    const int lane = tid & 63;
    const int wv   = tid >> 6;
    const int bpb  = NN / QPB;
    const int batch    = blockIdx.x / bpb;
    const int nodeBase = (blockIdx.x % bpb) * QPB;

    const float* cb = coords + (size_t)batch * NN * 3;

    // ---- staging: contiguous writes across lanes -> conflict-free ----
    for (int p = tid; p < NN; p += BLOCK) {
        float x = cb[3*p], y = cb[3*p+1], z = cb[3*p+2];
        pts[p] = make_float4(x, y, z, -0.5f * (x*x + y*y + z*z));
    }
    if (tid < 256) sW[tid] = tpw[tid];
    __syncthreads();

    const int q0 = nodeBase + wv * QPW;          // this wave's 4 query nodes
    const float4 P0 = pts[q0],   P1 = pts[q0+1];
    const float4 P2 = pts[q0+2], P3 = pts[q0+3];
    const float x0 = P0.x, y0 = P0.y, z0 = P0.z;
    const float x1 = P1.x, y1 = P1.y, z1 = P1.z;
    const float x2 = P2.x, y2 = P2.y, z2 = P2.z;
    const float x3 = P3.x, y3 = P3.y, z3 = P3.z;

    const f32x2 qAx = {x0, x1}, qAy = {y0, y1}, qAz = {z0, z1};
    const f32x2 qBx = {x2, x3}, qBy = {y2, y3}, qBz = {z2, z3};

    // ---- phase 1: diagonal scan, 4 top-2 ladders per LDS read ----
    // lane reads slot c of its column at pts[(c<<6) | (lane^c)]; a column's
    // 64 entries then span all 32 banks (conflict-free replay rescans).
    float b0 = -BIGF, s0 = -BIGF, b1 = -BIGF, s1 = -BIGF;
    float b2 = -BIGF, s2 = -BIGF, b3 = -BIGF, s3 = -BIGF;
    int bi0 = -1, si0 = -1, bi1 = -1, si1 = -1;
    int bi2 = -1, si2 = -1, bi3 = -1, si3 = -1;

    #pragma unroll 4
    for (int c = 0; c < NN / 64; ++c) {
        int j = (c << 6) | (lane ^ c);
        float4 P = pts[j];
        f32x2 Px = {P.x, P.x}, Py = {P.y, P.y}, Pz = {P.z, P.z}, Pw = {P.w, P.w};
        f32x2 dA = __builtin_elementwise_fma(Px, qAx,
                   __builtin_elementwise_fma(Py, qAy,
                   __builtin_elementwise_fma(Pz, qAz, Pw)));
        f32x2 dB = __builtin_elementwise_fma(Px, qBx,
                   __builtin_elementwise_fma(Py, qBy,
                   __builtin_elementwise_fma(Pz, qBz, Pw)));
        float d0 = dA.x, d1 = dA.y, d2 = dB.x, d3 = dB.y;
        LADDER(d0, b0, bi0, s0, si0)
        LADDER(d1, b1, bi1, s1, si1)
        LADDER(d2, b2, bi2, s2, si2)
        LADDER(d3, b3, bi3, s3, si3)
    }

    // self is its column's max (d2=0): demote; also purge self from s slot
    if (bi0 == q0  ) { b0 = s0; bi0 = si0; s0 = -BIGF; si0 = -1; }
    if (bi1 == q0+1) { b1 = s1; bi1 = si1; s1 = -BIGF; si1 = -1; }
    if (bi2 == q0+2) { b2 = s2; bi2 = si2; s2 = -BIGF; si2 = -1; }
    if (bi3 == q0+3) { b3 = s3; bi3 = si3; s3 = -BIGF; si3 = -1; }
    if (si0 == q0  ) { s0 = -BIGF; si0 = -1; }
    if (si1 == q0+1) { s1 = -BIGF; si1 = -1; }
    if (si2 == q0+2) { s2 = -BIGF; si2 = -1; }
    if (si3 == q0+3) { s3 = -BIGF; si3 = -1; }

    // ---- phase 2: 16 rounds, 4 queries' DPP chains interleaved ----
    unsigned long long used0 = 0ull, used1 = 0ull, used2 = 0ull, used3 = 0ull;
    int selIdx = 0;                     // lane 16*q + r owns edge r of query q

    #pragma unroll 1
    for (int r = 0; r < KNEI; ++r) {
        float f0 = b0, f1 = b1, f2 = b2, f3 = b3;
#define MS4(CTRL) f0 = dppmax_step<CTRL>(f0); f1 = dppmax_step<CTRL>(f1); \
                  f2 = dppmax_step<CTRL>(f2); f3 = dppmax_step<CTRL>(f3);
        MS4(0x111) MS4(0x112) MS4(0x114) MS4(0x118) MS4(0x142) MS4(0x143)
#undef MS4
        float M0 = rlanef(f0, 63), M1 = rlanef(f1, 63);
        float M2 = rlanef(f2, 63), M3 = rlanef(f3, 63);
        unsigned long long k0 = __ballot(b0 == M0), k1 = __ballot(b1 == M1);
        unsigned long long k2 = __ballot(b2 == M2), k3 = __ballot(b3 == M3);
        int w0 = __ffsll(k0) - 1, w1 = __ffsll(k1) - 1;
        int w2 = __ffsll(k2) - 1, w3 = __ffsll(k3) - 1;
        int mi0 = rlane(bi0, w0), mi1 = rlane(bi1, w1);
        int mi2 = rlane(bi2, w2), mi3 = rlane(bi3, w3);

        if (lane == r     ) selIdx = mi0;
        if (lane == r + 16) selIdx = mi1;
        if (lane == r + 32) selIdx = mi2;
        if (lane == r + 48) selIdx = mi3;

        bool n0 = rlane(si0, w0) == -1, n1 = rlane(si1, w1) == -1;
        bool n2 = rlane(si2, w2) == -1, n3 = rlane(si3, w3) == -1;

        if (lane == w0) { used0 |= 1ull << ((unsigned)(bi0 >> 6) & 63u);
                          b0 = s0; bi0 = si0; s0 = -BIGF; si0 = -1; }
        if (lane == w1) { used1 |= 1ull << ((unsigned)(bi1 >> 6) & 63u);
                          b1 = s1; bi1 = si1; s1 = -BIGF; si1 = -1; }
        if (lane == w2) { used2 |= 1ull << ((unsigned)(bi2 >> 6) & 63u);
                          b2 = s2; bi2 = si2; s2 = -BIGF; si2 = -1; }
        if (lane == w3) { used3 |= 1ull << ((unsigned)(bi3 >> 6) & 63u);
                          b3 = s3; bi3 = si3; s3 = -BIGF; si3 = -1; }

        if (n0 | n1 | n2 | n3) {       // uniform, rare (~2 per query total)
            if (n0) {
                unsigned long long uw =
                    ((unsigned long long)(unsigned)rlane((int)(used0 >> 32), w0) << 32)
                    | (unsigned)rlane((int)(used0 & 0xffffffffull), w0);
                replay_fill(pts, w0, x0, y0, z0, q0,   uw, lane, b0, bi0, s0, si0);
            }
            if (n1) {
                unsigned long long uw =
                    ((unsigned long long)(unsigned)rlane((int)(used1 >> 32), w1) << 32)
                    | (unsigned)rlane((int)(used1 & 0xffffffffull), w1);
                replay_fill(pts, w1, x1, y1, z1, q0+1, uw, lane, b1, bi1, s1, si1);
            }
            if (n2) {
                unsigned long long uw =
                    ((unsigned long long)(unsigned)rlane((int)(used2 >> 32), w2) << 32)
                    | (unsigned)rlane((int)(used2 & 0xffffffffull), w2);
                replay_fill(pts, w2, x2, y2, z2, q0+2, uw, lane, b2, bi2, s2, si2);
            }
            if (n3) {
                unsigned long long uw =
                    ((unsigned long long)(unsigned)rlane((int)(used3 >> 32), w3) << 32)
                    | (unsigned)rlane((int)(used3 & 0xffffffffull), w3);
                replay_fill(pts, w3, x3, y3, z3, q0+3, uw, lane, b3, bi3, s3, si3);
            }
        }
    }

    // ---- epilogue: each lane computes its edge's 24 S-components once ----
    const int eq = lane >> 4;
    float xq = (eq & 2) ? ((eq & 1) ? x3 : x2) : ((eq & 1) ? x1 : x0);
    float yq = (eq & 2) ? ((eq & 1) ? y3 : y2) : ((eq & 1) ? y1 : y0);
    float zq = (eq & 2) ? ((eq & 1) ? z3 : z2) : ((eq & 1) ? z1 : z0);

    float4 P = pts[selIdx];
    float rx = P.x - xq, ry = P.y - yq, rz = P.z - zq;   // sender - receiver
    float dist = sqrtf(rx*rx + ry*ry + rz*rz);
    float inv  = 1.0f / (dist + 1e-8f);
    float hx = rx * inv, hy = ry * inv, hz = rz * inv;
    float cu = fminf(dist / 10.0f, 1.0f);
    float gg[8], ssum = 0.0f;
    #pragma unroll
    for (int v = 0; v < 8; ++v) {
        float d = cu - (float)v * (1.0f / 7.0f);
        gg[v] = expf(d * d * -32.0f);
        ssum += gg[v];
    }
    float is = 1.0f / ssum;
    float S[24];
    #pragma unroll
    for (int v = 0; v < 8; ++v) {
        float rbv = gg[v] * is;
        S[3*v]   = rbv * hx;
        S[3*v+1] = rbv * hy;
        S[3*v+2] = rbv * hz;
    }
    #pragma unroll
    for (int t = 0; t < 24; ++t) S[t] = row16_sum_dpp(S[t]);

    float wcol[8];
    #pragma unroll
    for (int v = 0; v < 8; ++v) wcol[v] = sW[32*v + (lane & 31)];

    const float scale = 0.036084391824351613f;   // 1/(16*sqrt(3))
    const float4 z4 = make_float4(0.f, 0.f, 0.f, 0.f);

    #pragma unroll
    for (int q = 0; q < QPW; ++q) {
        const int gq = batch * NN + q0 + q;
        float sg[24];
        #pragma unroll
        for (int t = 0; t < 24; ++t) sg[t] = rlanef(S[t], 16 * q + 15);

        float* onode = out + (size_t)gq * 464;
        float4* o4 = (float4*)onode;
        if (lane < 16)       o4[lane] = z4;          // ch 0..63
        else if (lane < 36)  o4[lane + 24] = z4;     // ch 160..239

        if (lane < 32) {
            float a0 = 0.f, a1 = 0.f, a2 = 0.f;
            #pragma unroll
            for (int v = 0; v < 8; ++v) {
                a0 = fmaf(wcol[v], sg[3*v],   a0);
                a1 = fmaf(wcol[v], sg[3*v+1], a1);
                a2 = fmaf(wcol[v], sg[3*v+2], a2);
            }
            onode[64 + 3*lane]     = a0 * scale;
            onode[64 + 3*lane + 1] = a1 * scale;
            onode[64 + 3*lane + 2] = a2 * scale;
        }

        const int at = atypes[gq];
        const int rt = rtypes[gq];
        if (lane < 56) {
            float4 v = (lane < 28)
                ? ((const float4*)(aemb + 112*at))[lane]
                : ((const float4*)(remb + 112*rt))[lane - 28];
            o4[60 + lane] = v;
        }
    }
}

extern "C" void kernel_launch(void* const* d_in, const int* in_sizes, int n_in,
                              void* d_out, int out_size, void* d_ws, size_t ws_size,
                              hipStream_t stream)
{
    const float* coords = (const float*)d_in[0];
    const int*   at     = (const int*)  d_in[1];
    const int*   rt     = (const int*)  d_in[2];
    const float* tpw    = (const float*)d_in[3];
    const float* ae     = (const float*)d_in[4];
    const float* re     = (const float*)d_in[5];
    float* out = (float*)d_out;

    const int B = in_sizes[1] / NN;                  // 8
    dim3 grid(B * (NN / QPB));
    protein_enc_kernel<<<grid, BLOCK, 0, stream>>>(coords, at, rt, tpw, ae, re, out);
}

// Round 11
// 85.420 us; speedup vs baseline: 1.2136x; 1.0623x over previous
//
#include <hip/hip_runtime.h>
#include <hip/hip_bf16.h>

#define NN    4096
#define KNEI  16
#define QPW   4              // query nodes per wave
#define WPB   16             // waves per block
#define BLOCK (WPB * 64)
#define QPB   (WPB * QPW)    // 64 queries per block
#define BIGF  3.0e38f

typedef float f32x2 __attribute__((ext_vector_type(2)));

__device__ __forceinline__ int rlane(int v, int l)
{ return __builtin_amdgcn_readlane(v, l); }
__device__ __forceinline__ float rlanef(float v, int l)
{ return __int_as_float(__builtin_amdgcn_readlane(__float_as_int(v), l)); }

// ---- DPP argmax step: (f,i) joint max, index carried via cndmask ----
template<int CTRL>
__device__ __forceinline__ void amax_step(float& f, int& i)
{
    int fs = __builtin_amdgcn_update_dpp(__float_as_int(f), __float_as_int(f),
                                         CTRL, 0xF, 0xF, false);
    int is = __builtin_amdgcn_update_dpp(i, i, CTRL, 0xF, 0xF, false);
    float ff = __int_as_float(fs);
    bool gt = ff > f;
    f = gt ? ff : f;
    i = gt ? is : i;
}

// full-wave argmax (index-carry); (M, mi) broadcast via lane 63
__device__ __forceinline__ void wave_amax(float f, int i, float& M, int& mi)
{
    amax_step<0x111>(f, i); amax_step<0x112>(f, i); amax_step<0x114>(f, i);
    amax_step<0x118>(f, i); amax_step<0x142>(f, i); amax_step<0x143>(f, i);
    M  = rlanef(f, 63);
    mi = rlane(i, 63);
}

// row-16 all-lanes argmax via rotate-reduce: EVERY lane of each 16-lane row
// ends with the row's (max, idx) — no readlane, no ballot.
__device__ __forceinline__ void row_amax(float& f, int& i)
{
    amax_step<0x121>(f, i); amax_step<0x122>(f, i);
    amax_step<0x124>(f, i); amax_step<0x128>(f, i);
}

__device__ __forceinline__ float row16_sum_dpp(float v)  // lane 16r+15 -> row sum
{
    float f = v;
#define STEPA(CTRL)                                                          \
    { int s_ = __builtin_amdgcn_update_dpp(0, __float_as_int(f),             \
               (CTRL), 0xF, 0xF, true);                                      \
      f += __int_as_float(s_); }
    STEPA(0x111) STEPA(0x112) STEPA(0x114) STEPA(0x118)
#undef STEPA
    return f;
}

__device__ __forceinline__ float bpermf(int abyte, float v)
{ return __int_as_float(__builtin_amdgcn_ds_bpermute(abyte, __float_as_int(v))); }
__device__ __forceinline__ int bpermi(int abyte, int v)
{ return __builtin_amdgcn_ds_bpermute(abyte, v); }

__device__ __forceinline__ float sel4f(float a, float b, float c, float d, int q)
{
    float lo = (q & 1) ? b : a;
    float hi = (q & 1) ? d : c;
    return (q & 2) ? hi : lo;
}
__device__ __forceinline__ int sel4i(int a, int b, int c, int d, int q)
{
    int lo = (q & 1) ? b : a;
    int hi = (q & 1) ? d : c;
    return (q & 2) ? hi : lo;
}

// s_new = median(d, s_old, b_old); strict > keeps first-seen on ties
#define LADDER(d, b, bi, s, si)                                   \
    {  bool gtb = (d) > (b); bool gts = (d) > (s);                \
       (s)  = __builtin_amdgcn_fmed3f((d), (s), (b));             \
       (si) = gtb ? (bi) : (gts ? j : (si));                      \
       (b)  = fmaxf((b), (d));                                    \
       (bi) = gtb ? j : (bi); }

// rare wave-wide replay for query q: recompute column colq's top-2 unextracted
#define REPLAY(q, xq, yq, zq)                                                \
    {   int colq = rlane(col, 16 * (q));                                     \
        int csq  = rlane(cs,  16 * (q));                                     \
        int j2 = (lane << 6) | (colq ^ lane);                                \
        float4 P = pts[j2];                                                  \
        float scr = fmaf(P.x, (xq), fmaf(P.y, (yq), fmaf(P.z, (zq), P.w)));  \
        if (j2 == q0 + (q)) scr = -BIGF;                                     \
        _Pragma("unroll")                                                    \
        for (int t = 0; t < KNEI; ++t) {                                     \
            int sv = rlane(selIdx, 16 * (q) + t);                            \
            if (j2 == sv) scr = -BIGF;                                       \
        }                                                                    \
        float M1; int i1;                                                    \
        wave_amax(scr, j2, M1, i1);                                          \
        float scr2 = (j2 == i1) ? -BIGF : scr;                               \
        float M2; int i2;                                                    \
        wave_amax(scr2, j2, M2, i2);                                         \
        bool ow = (lane == 16 * (q) + (colq & 15));                          \
        if (csq == 0) { pb0 = ow ? M1 : pb0; pbi0 = ow ? i1 : pbi0;          \
                        ps0 = ow ? M2 : ps0; psi0 = ow ? i2 : psi0; }        \
        else if (csq == 1) { pb1 = ow ? M1 : pb1; pbi1 = ow ? i1 : pbi1;     \
                        ps1 = ow ? M2 : ps1; psi1 = ow ? i2 : psi1; }        \
        else if (csq == 2) { pb2 = ow ? M1 : pb2; pbi2 = ow ? i1 : pbi2;     \
                        ps2 = ow ? M2 : ps2; psi2 = ow ? i2 : psi2; }        \
        else          { pb3 = ow ? M1 : pb3; pbi3 = ow ? i1 : pbi3;          \
                        ps3 = ow ? M2 : ps3; psi3 = ow ? i2 : psi3; }        \
    }

// per-slot promote inside the round loop
#define PROMOTE(k, pb, pbi, ps, psi)                                         \
    {   bool pk = own && (cs == (k));                                        \
        exh = exh || (pk && ((psi) == -1));                                  \
        (pb)  = pk ? (ps)  : (pb);                                           \
        (pbi) = pk ? (psi) : (pbi);                                          \
        (ps)  = pk ? -BIGF : (ps);                                           \
        (psi) = pk ? -1    : (psi);                                          \
    }

__global__ __launch_bounds__(BLOCK, 8)
void protein_enc_kernel(const float* __restrict__ coords,
                        const int*   __restrict__ atypes,
                        const int*   __restrict__ rtypes,
                        const float* __restrict__ tpw,
                        const float* __restrict__ aemb,
                        const float* __restrict__ remb,
                        float* __restrict__ out)
{
    __shared__ float4 pts[NN];      // x, y, z, -n2/2
    __shared__ float  sW[8 * 32];

    const int tid  = threadIdx.x;
    const int lane = tid & 63;
    const int wv   = tid >> 6;
    const int bpb  = NN / QPB;
    const int batch    = blockIdx.x / bpb;
    const int nodeBase = (blockIdx.x % bpb) * QPB;

    const float* cb = coords + (size_t)batch * NN * 3;

    // ---- staging: contiguous writes across lanes -> conflict-free ----
    for (int p = tid; p < NN; p += BLOCK) {
        float x = cb[3*p], y = cb[3*p+1], z = cb[3*p+2];
        pts[p] = make_float4(x, y, z, -0.5f * (x*x + y*y + z*z));
    }
    if (tid < 256) sW[tid] = tpw[tid];
    __syncthreads();

    const int q0 = nodeBase + wv * QPW;          // this wave's 4 query nodes
    const float4 P0 = pts[q0],   P1 = pts[q0+1];
    const float4 P2 = pts[q0+2], P3 = pts[q0+3];
    const float x0 = P0.x, y0 = P0.y, z0 = P0.z;
    const float x1 = P1.x, y1 = P1.y, z1 = P1.z;
    const float x2 = P2.x, y2 = P2.y, z2 = P2.z;
    const float x3 = P3.x, y3 = P3.y, z3 = P3.z;

    const f32x2 qAx = {x0, x1}, qAy = {y0, y1}, qAz = {z0, z1};
    const f32x2 qBx = {x2, x3}, qBy = {y2, y3}, qBz = {z2, z3};

    // ---- phase 1: diagonal scan, 4 top-2 ladders per LDS read ----
    float b0 = -BIGF, s0 = -BIGF, b1 = -BIGF, s1 = -BIGF;
    float b2 = -BIGF, s2 = -BIGF, b3 = -BIGF, s3 = -BIGF;
    int bi0 = -1, si0 = -1, bi1 = -1, si1 = -1;
    int bi2 = -1, si2 = -1, bi3 = -1, si3 = -1;

    #pragma unroll 4
    for (int c = 0; c < NN / 64; ++c) {
        int j = (c << 6) | (lane ^ c);
        float4 P = pts[j];
        f32x2 Px = {P.x, P.x}, Py = {P.y, P.y}, Pz = {P.z, P.z}, Pw = {P.w, P.w};
        f32x2 dA = __builtin_elementwise_fma(Px, qAx,
                   __builtin_elementwise_fma(Py, qAy,
                   __builtin_elementwise_fma(Pz, qAz, Pw)));
        f32x2 dB = __builtin_elementwise_fma(Px, qBx,
                   __builtin_elementwise_fma(Py, qBy,
                   __builtin_elementwise_fma(Pz, qBz, Pw)));
        float d0 = dA.x, d1 = dA.y, d2 = dB.x, d3 = dB.y;
        LADDER(d0, b0, bi0, s0, si0)
        LADDER(d1, b1, bi1, s1, si1)
        LADDER(d2, b2, bi2, s2, si2)
        LADDER(d3, b3, bi3, s3, si3)
    }

    // self is its column's max (d2=0): demote; also purge self from s slot
    if (bi0 == q0  ) { b0 = s0; bi0 = si0; s0 = -BIGF; si0 = -1; }
    if (bi1 == q0+1) { b1 = s1; bi1 = si1; s1 = -BIGF; si1 = -1; }
    if (bi2 == q0+2) { b2 = s2; bi2 = si2; s2 = -BIGF; si2 = -1; }
    if (bi3 == q0+3) { b3 = s3; bi3 = si3; s3 = -BIGF; si3 = -1; }
    if (si0 == q0  ) { s0 = -BIGF; si0 = -1; }
    if (si1 == q0+1) { s1 = -BIGF; si1 = -1; }
    if (si2 == q0+2) { s2 = -BIGF; si2 = -1; }
    if (si3 == q0+3) { s3 = -BIGF; si3 = -1; }

    // ---- redistribute: query q's 64-column pool -> lane group 16q..16q+15,
    //      each group-lane t owns columns {t, t+16, t+32, t+48} (slots 0..3)
    const int q = lane >> 4;
    const int gt = lane & 15;
    float pb0, pb1, pb2, pb3, ps0, ps1, ps2, ps3;
    int   pbi0, pbi1, pbi2, pbi3, psi0, psi1, psi2, psi3;
    {
        const int ab = gt << 2;     // byte addr of source lane (column id)
#define PULL(K, PB, PS, PBI, PSI)                                            \
        {   int a = ab + ((K) << 6);                                         \
            PB  = sel4f(bpermf(a,b0),  bpermf(a,b1),  bpermf(a,b2),  bpermf(a,b3),  q); \
            PS  = sel4f(bpermf(a,s0),  bpermf(a,s1),  bpermf(a,s2),  bpermf(a,s3),  q); \
            PBI = sel4i(bpermi(a,bi0), bpermi(a,bi1), bpermi(a,bi2), bpermi(a,bi3), q); \
            PSI = sel4i(bpermi(a,si0), bpermi(a,si1), bpermi(a,si2), bpermi(a,si3), q); \
        }
        PULL(0, pb0, ps0, pbi0, psi0)
        PULL(1, pb1, ps1, pbi1, psi1)
        PULL(2, pb2, ps2, pbi2, psi2)
        PULL(3, pb3, ps3, pbi3, psi3)
#undef PULL
    }

    // ---- phase 2: 16 rounds; all 4 groups extract concurrently ----
    int selIdx = -1;                 // lane 16q + r holds edge r of query q
    const int myR = gt;

    #pragma unroll 1
    for (int r = 0; r < KNEI; ++r) {
        // local argmax over this lane's 4 column-bests (idx packs slot<<12|j)
        float f = pb0; int m = pbi0;                    // slot 0
        { bool g = pb1 > f; f = g ? pb1 : f; m = g ? ((1<<12)|pbi1) : m; }
        { bool g = pb2 > f; f = g ? pb2 : f; m = g ? ((2<<12)|pbi2) : m; }
        { bool g = pb3 > f; f = g ? pb3 : f; m = g ? ((3<<12)|pbi3) : m; }
        row_amax(f, m);             // every lane of the group now has (f,m)

        int j   = m & 4095;
        int cs  = m >> 12;                       // winner's slot at owner
        int col = (j & 63) ^ (j >> 6);           // winner's column id
        bool own = (myR == (col & 15));

        if (myR == r) selIdx = j;

        bool exh = false;
        PROMOTE(0, pb0, pbi0, ps0, psi0)
        PROMOTE(1, pb1, pbi1, ps1, psi1)
        PROMOTE(2, pb2, pbi2, ps2, psi2)
        PROMOTE(3, pb3, pbi3, ps3, psi3)

        unsigned long long ex = __ballot(exh);
        if (ex) {                                 // rare refill path
            if ((ex >>  0) & 0xFFFFull) REPLAY(0, x0, y0, z0)
            if ((ex >> 16) & 0xFFFFull) REPLAY(1, x1, y1, z1)
            if ((ex >> 32) & 0xFFFFull) REPLAY(2, x2, y2, z2)
            if ((ex >> 48) & 0xFFFFull) REPLAY(3, x3, y3, z3)
        }
    }

    // ---- epilogue: each lane computes its edge's 24 S-components once ----
    float xq = (q & 2) ? ((q & 1) ? x3 : x2) : ((q & 1) ? x1 : x0);
    float yq = (q & 2) ? ((q & 1) ? y3 : y2) : ((q & 1) ? y1 : y0);
    float zq = (q & 2) ? ((q & 1) ? z3 : z2) : ((q & 1) ? z1 : z0);

    float4 P = pts[selIdx];
    float rx = P.x - xq, ry = P.y - yq, rz = P.z - zq;   // sender - receiver
    float dist = sqrtf(rx*rx + ry*ry + rz*rz);
    float inv  = 1.0f / (dist + 1e-8f);
    float hx = rx * inv, hy = ry * inv, hz = rz * inv;
    float cu = fminf(dist / 10.0f, 1.0f);
    float gg[8], ssum = 0.0f;
    #pragma unroll
    for (int v = 0; v < 8; ++v) {
        float d = cu - (float)v * (1.0f / 7.0f);
        gg[v] = expf(d * d * -32.0f);
        ssum += gg[v];
    }
    float is = 1.0f / ssum;
    float S[24];
    #pragma unroll
    for (int v = 0; v < 8; ++v) {
        float rbv = gg[v] * is;
        S[3*v]   = rbv * hx;
        S[3*v+1] = rbv * hy;
        S[3*v+2] = rbv * hz;
    }
    #pragma unroll
    for (int t = 0; t < 24; ++t) S[t] = row16_sum_dpp(S[t]);

    float wcol[8];
    #pragma unroll
    for (int v = 0; v < 8; ++v) wcol[v] = sW[32*v + (lane & 31)];

    const float scale = 0.036084391824351613f;   // 1/(16*sqrt(3))
    const float4 z4 = make_float4(0.f, 0.f, 0.f, 0.f);

    #pragma unroll
    for (int qq = 0; qq < QPW; ++qq) {
        const int gq = batch * NN + q0 + qq;
        float sg[24];
        #pragma unroll
        for (int t = 0; t < 24; ++t) sg[t] = rlanef(S[t], 16 * qq + 15);

        float* onode = out + (size_t)gq * 464;
        float4* o4 = (float4*)onode;
        if (lane < 16)       o4[lane] = z4;          // ch 0..63
        else if (lane < 36)  o4[lane + 24] = z4;     // ch 160..239

        if (lane < 32) {
            float a0 = 0.f, a1 = 0.f, a2 = 0.f;
            #pragma unroll
            for (int v = 0; v < 8; ++v) {
                a0 = fmaf(wcol[v], sg[3*v],   a0);
                a1 = fmaf(wcol[v], sg[3*v+1], a1);
                a2 = fmaf(wcol[v], sg[3*v+2], a2);
            }
            onode[64 + 3*lane]     = a0 * scale;
            onode[64 + 3*lane + 1] = a1 * scale;
            onode[64 + 3*lane + 2] = a2 * scale;
        }

        const int at = atypes[gq];
        const int rt = rtypes[gq];
        if (lane < 56) {
            float4 v = (lane < 28)
                ? ((const float4*)(aemb + 112*at))[lane]
                : ((const float4*)(remb + 112*rt))[lane - 28];
            o4[60 + lane] = v;
        }
    }
}

extern "C" void kernel_launch(void* const* d_in, const int* in_sizes, int n_in,
                              void* d_out, int out_size, void* d_ws, size_t ws_size,
                              hipStream_t stream)
{
    const float* coords = (const float*)d_in[0];
    const int*   at     = (const int*)  d_in[1];
    const int*   rt     = (const int*)  d_in[2];
    const float* tpw    = (const float*)d_in[3];
    const float* ae     = (const float*)d_in[4];
    const float* re     = (const float*)d_in[5];
    float* out = (float*)d_out;

    const int B = in_sizes[1] / NN;                  // 8
    dim3 grid(B * (NN / QPB));
    protein_enc_kernel<<<grid, BLOCK, 0, stream>>>(coords, at, rt, tpw, ae, re, out);
}

// Round 12
// 73.798 us; speedup vs baseline: 1.4047x; 1.1575x over previous
//
#include <hip/hip_runtime.h>
#include <hip/hip_bf16.h>

#define NN    4096
#define KNEI  16
#define QPW   4              // query nodes per wave
#define WPB   16             // waves per block
#define BLOCK (WPB * 64)
#define QPB   (WPB * QPW)    // 64 queries per block
#define NEGB  -3.0e38f
#define PACKM 0xFFFFFFC0

typedef float f32x2 __attribute__((ext_vector_type(2)));

__device__ __forceinline__ int rlane(int v, int l)
{ return __builtin_amdgcn_readlane(v, l); }
__device__ __forceinline__ float rlanef(float v, int l)
{ return __int_as_float(__builtin_amdgcn_readlane(__float_as_int(v), l)); }

// ---- DPP argmax step: (f,i) joint max, index carried via cndmask ----
template<int CTRL>
__device__ __forceinline__ void amax_step(float& f, int& i)
{
    int fs = __builtin_amdgcn_update_dpp(__float_as_int(f), __float_as_int(f),
                                         CTRL, 0xF, 0xF, false);
    int is = __builtin_amdgcn_update_dpp(i, i, CTRL, 0xF, 0xF, false);
    float ff = __int_as_float(fs);
    bool gt = ff > f;
    f = gt ? ff : f;
    i = gt ? is : i;
}

// full-wave argmax (index-carry); (M, mi) broadcast via lane 63
__device__ __forceinline__ void wave_amax(float f, int i, float& M, int& mi)
{
    amax_step<0x111>(f, i); amax_step<0x112>(f, i); amax_step<0x114>(f, i);
    amax_step<0x118>(f, i); amax_step<0x142>(f, i); amax_step<0x143>(f, i);
    M  = rlanef(f, 63);
    mi = rlane(i, 63);
}

// row-16 all-lanes argmax via rotate-reduce (row_ror:1/2/4/8)
__device__ __forceinline__ void row_amax(float& f, int& i)
{
    amax_step<0x121>(f, i); amax_step<0x122>(f, i);
    amax_step<0x124>(f, i); amax_step<0x128>(f, i);
}

__device__ __forceinline__ float row16_sum_dpp(float v)  // lane 16r+15 -> row sum
{
    float f = v;
#define STEPA(CTRL)                                                          \
    { int s_ = __builtin_amdgcn_update_dpp(0, __float_as_int(f),             \
               (CTRL), 0xF, 0xF, true);                                      \
      f += __int_as_float(s_); }
    STEPA(0x111) STEPA(0x112) STEPA(0x114) STEPA(0x118)
#undef STEPA
    return f;
}

__device__ __forceinline__ float bpermf(int abyte, float v)
{ return __int_as_float(__builtin_amdgcn_ds_bpermute(abyte, __float_as_int(v))); }

__device__ __forceinline__ float sel4f(float a, float b, float c, float d, int q)
{
    float lo = (q & 1) ? b : a;
    float hi = (q & 1) ? d : c;
    return (q & 2) ? hi : lo;
}

// packed ladder: index lives in low 6 mantissa bits (c = J>>6)
#define LADDER(dp, b, s)                                          \
    {  (s) = __builtin_amdgcn_fmed3f((dp), (s), (b));             \
       (b) = fmaxf((b), (dp)); }

// purge self (always its column's packed max, possibly packed 2nd)
#define SELFFIX(q, b, s)                                                     \
    {  int cb_ = __float_as_int(b) & 63;                                     \
       if ((((cb_) << 6) | (lane ^ cb_)) == q0 + (q)) { (b) = (s); (s) = NEGB; } \
       int cs_ = __float_as_int(s) & 63;                                     \
       if ((((cs_) << 6) | (lane ^ cs_)) == q0 + (q)) { (s) = NEGB; } }

// rare wave-wide replay for query q: rebuild column colq's top-2 unselected
#define REPLAY(q, xq, yq, zq)                                                \
    {   int colq = rlane(colw, 16 * (q));                                    \
        int kq   = rlane(kw,   16 * (q));                                    \
        int j2 = (lane << 6) | (colq ^ lane);                                \
        float4 P = pts[j2];                                                  \
        float scr = fmaf(P.x, (xq), fmaf(P.y, (yq), fmaf(P.z, (zq), P.w)));  \
        float sf = __int_as_float((__float_as_int(scr) & PACKM) | lane);     \
        if (j2 == q0 + (q)) sf = NEGB;                                       \
        _Pragma("unroll")                                                    \
        for (int t = 0; t < KNEI; ++t) {                                     \
            int sv = rlane(selIdx, 16 * (q) + t);                            \
            if (j2 == sv) sf = NEGB;                                         \
        }                                                                    \
        float M1; int i1;                                                    \
        wave_amax(sf, j2, M1, i1);                                           \
        float sf2 = (j2 == i1) ? NEGB : sf;                                  \
        float M2; int i2;                                                    \
        wave_amax(sf2, j2, M2, i2);                                          \
        bool ow = (lane == 16 * (q) + (colq & 15));                          \
        if (kq == 0)      { pb0 = ow ? M1 : pb0; ps0 = ow ? M2 : ps0; }      \
        else if (kq == 1) { pb1 = ow ? M1 : pb1; ps1 = ow ? M2 : ps1; }      \
        else if (kq == 2) { pb2 = ow ? M1 : pb2; ps2 = ow ? M2 : ps2; }      \
        else              { pb3 = ow ? M1 : pb3; ps3 = ow ? M2 : ps3; }      \
    }

#define PROMOTE(k, pb, ps)                                                   \
    {   bool pk = own && (kw == (k));                                        \
        exh = exh || (pk && ((ps) == NEGB));                                 \
        (pb) = pk ? (ps)  : (pb);                                            \
        (ps) = pk ? NEGB : (ps);                                             \
    }

__global__ __launch_bounds__(BLOCK, 8)
void protein_enc_kernel(const float* __restrict__ coords,
                        const int*   __restrict__ atypes,
                        const int*   __restrict__ rtypes,
                        const float* __restrict__ tpw,
                        const float* __restrict__ aemb,
                        const float* __restrict__ remb,
                        float* __restrict__ out)
{
    __shared__ float4 pts[NN];      // x, y, z, -n2/2
    __shared__ float  sW[8 * 32];

    const int tid  = threadIdx.x;
    const int lane = tid & 63;
    const int wv   = tid >> 6;
    const int bpb  = NN / QPB;
    const int batch    = blockIdx.x / bpb;
    const int nodeBase = (blockIdx.x % bpb) * QPB;

    const float* cb = coords + (size_t)batch * NN * 3;

    // ---- staging: contiguous writes across lanes -> conflict-free ----
    for (int p = tid; p < NN; p += BLOCK) {
        float x = cb[3*p], y = cb[3*p+1], z = cb[3*p+2];
        pts[p] = make_float4(x, y, z, -0.5f * (x*x + y*y + z*z));
    }
    if (tid < 256) sW[tid] = tpw[tid];
    __syncthreads();

    const int q0 = nodeBase + wv * QPW;          // this wave's 4 query nodes
    const float4 P0 = pts[q0],   P1 = pts[q0+1];
    const float4 P2 = pts[q0+2], P3 = pts[q0+3];
    const float x0 = P0.x, y0 = P0.y, z0 = P0.z;
    const float x1 = P1.x, y1 = P1.y, z1 = P1.z;
    const float x2 = P2.x, y2 = P2.y, z2 = P2.z;
    const float x3 = P3.x, y3 = P3.y, z3 = P3.z;

    const f32x2 qAx = {x0, x1}, qAy = {y0, y1}, qAz = {z0, z1};
    const f32x2 qBx = {x2, x3}, qBy = {y2, y3}, qBz = {z2, z3};

    // ---- phase 1: diagonal scan, packed top-2 ladders (2 FP ops each) ----
    float b0 = NEGB, s0 = NEGB, b1 = NEGB, s1 = NEGB;
    float b2 = NEGB, s2 = NEGB, b3 = NEGB, s3 = NEGB;

    #pragma unroll 8
    for (int c = 0; c < NN / 64; ++c) {
        int j = (c << 6) | (lane ^ c);
        float4 P = pts[j];
        f32x2 Px = {P.x, P.x}, Py = {P.y, P.y}, Pz = {P.z, P.z}, Pw = {P.w, P.w};
        f32x2 dA = __builtin_elementwise_fma(Px, qAx,
                   __builtin_elementwise_fma(Py, qAy,
                   __builtin_elementwise_fma(Pz, qAz, Pw)));
        f32x2 dB = __builtin_elementwise_fma(Px, qBx,
                   __builtin_elementwise_fma(Py, qBy,
                   __builtin_elementwise_fma(Pz, qBz, Pw)));
        float d0 = __int_as_float((__float_as_int(dA.x) & PACKM) | c);
        float d1 = __int_as_float((__float_as_int(dA.y) & PACKM) | c);
        float d2 = __int_as_float((__float_as_int(dB.x) & PACKM) | c);
        float d3 = __int_as_float((__float_as_int(dB.y) & PACKM) | c);
        LADDER(d0, b0, s0)
        LADDER(d1, b1, s1)
        LADDER(d2, b2, s2)
        LADDER(d3, b3, s3)
    }

    SELFFIX(0, b0, s0)
    SELFFIX(1, b1, s1)
    SELFFIX(2, b2, s2)
    SELFFIX(3, b3, s3)

    // ---- redistribute: query q -> lanes 16q..16q+15; lane t owns columns
    //      {t, t+16, t+32, t+48} as slots 0..3 (column implicit!)
    const int q  = lane >> 4;
    const int gt = lane & 15;
    float pb0, pb1, pb2, pb3, ps0, ps1, ps2, ps3;
    {
        const int ab = gt << 2;     // byte addr of source lane (column id)
#define PULL(K, PB, PS)                                                      \
        {   int a = ab + ((K) << 6);                                         \
            PB = sel4f(bpermf(a,b0), bpermf(a,b1), bpermf(a,b2), bpermf(a,b3), q); \
            PS = sel4f(bpermf(a,s0), bpermf(a,s1), bpermf(a,s2), bpermf(a,s3), q); \
        }
        PULL(0, pb0, ps0)
        PULL(1, pb1, ps1)
        PULL(2, pb2, ps2)
        PULL(3, pb3, ps3)
#undef PULL
    }

    // ---- phase 2: 16 rounds; 4 groups extract concurrently, no indices ----
    int selIdx = -1;                 // lane 16q + r holds edge r of query q

    #pragma unroll 1
    for (int r = 0; r < KNEI; ++r) {
        float f = fmaxf(fmaxf(pb0, pb1), fmaxf(pb2, pb3));
        int k = (f == pb3) ? 3 : ((f == pb2) ? 2 : ((f == pb1) ? 1 : 0));
        int cw = __float_as_int(f) & 63;
        int col = gt + (k << 4);
        int jl = (cw << 6) | (col ^ cw);
        int i = (k << 12) | jl;
        row_amax(f, i);             // every lane of the group now has (f,i)

        int j  = i & 4095;
        int kw = i >> 12;
        int colw = (j & 63) ^ (j >> 6);
        bool own = (gt == (colw & 15));

        if (gt == r) selIdx = j;

        bool exh = false;
        PROMOTE(0, pb0, ps0)
        PROMOTE(1, pb1, ps1)
        PROMOTE(2, pb2, ps2)
        PROMOTE(3, pb3, ps3)

        unsigned long long ex = __ballot(exh);
        if (ex) {                                 // rare refill path
            if ((ex >>  0) & 0xFFFFull) REPLAY(0, x0, y0, z0)
            if ((ex >> 16) & 0xFFFFull) REPLAY(1, x1, y1, z1)
            if ((ex >> 32) & 0xFFFFull) REPLAY(2, x2, y2, z2)
            if ((ex >> 48) & 0xFFFFull) REPLAY(3, x3, y3, z3)
        }
    }

    // ---- epilogue: each lane computes its edge's 24 S-components once ----
    float xq = (q & 2) ? ((q & 1) ? x3 : x2) : ((q & 1) ? x1 : x0);
    float yq = (q & 2) ? ((q & 1) ? y3 : y2) : ((q & 1) ? y1 : y0);
    float zq = (q & 2) ? ((q & 1) ? z3 : z2) : ((q & 1) ? z1 : z0);

    float4 P = pts[selIdx];
    float rx = P.x - xq, ry = P.y - yq, rz = P.z - zq;   // sender - receiver
    float dist = sqrtf(rx*rx + ry*ry + rz*rz);
    float inv  = 1.0f / (dist + 1e-8f);
    float hx = rx * inv, hy = ry * inv, hz = rz * inv;
    float cu = fminf(dist / 10.0f, 1.0f);
    float gg[8], ssum = 0.0f;
    #pragma unroll
    for (int v = 0; v < 8; ++v) {
        float d = cu - (float)v * (1.0f / 7.0f);
        gg[v] = expf(d * d * -32.0f);
        ssum += gg[v];
    }
    float is = 1.0f / ssum;
    float S[24];
    #pragma unroll
    for (int v = 0; v < 8; ++v) {
        float rbv = gg[v] * is;
        S[3*v]   = rbv * hx;
        S[3*v+1] = rbv * hy;
        S[3*v+2] = rbv * hz;
    }
    #pragma unroll
    for (int t = 0; t < 24; ++t) S[t] = row16_sum_dpp(S[t]);

    float wcol[8];
    #pragma unroll
    for (int v = 0; v < 8; ++v) wcol[v] = sW[32*v + (lane & 31)];

    const float scale = 0.036084391824351613f;   // 1/(16*sqrt(3))
    const float4 z4 = make_float4(0.f, 0.f, 0.f, 0.f);

    #pragma unroll
    for (int qq = 0; qq < QPW; ++qq) {
        const int gq = batch * NN + q0 + qq;
        float sg[24];
        #pragma unroll
        for (int t = 0; t < 24; ++t) sg[t] = rlanef(S[t], 16 * qq + 15);

        float* onode = out + (size_t)gq * 464;
        float4* o4 = (float4*)onode;
        if (lane < 16)       o4[lane] = z4;          // ch 0..63
        else if (lane < 36)  o4[lane + 24] = z4;     // ch 160..239

        if (lane < 32) {
            float a0 = 0.f, a1 = 0.f, a2 = 0.f;
            #pragma unroll
            for (int v = 0; v < 8; ++v) {
                a0 = fmaf(wcol[v], sg[3*v],   a0);
                a1 = fmaf(wcol[v], sg[3*v+1], a1);
                a2 = fmaf(wcol[v], sg[3*v+2], a2);
            }
            onode[64 + 3*lane]     = a0 * scale;
            onode[64 + 3*lane + 1] = a1 * scale;
            onode[64 + 3*lane + 2] = a2 * scale;
        }

        const int at = atypes[gq];
        const int rt = rtypes[gq];
        if (lane < 56) {
            float4 v = (lane < 28)
                ? ((const float4*)(aemb + 112*at))[lane]
                : ((const float4*)(remb + 112*rt))[lane - 28];
            o4[60 + lane] = v;
        }
    }
}

extern "C" void kernel_launch(void* const* d_in, const int* in_sizes, int n_in,
                              void* d_out, int out_size, void* d_ws, size_t ws_size,
                              hipStream_t stream)
{
    const float* coords = (const float*)d_in[0];
    const int*   at     = (const int*)  d_in[1];
    const int*   rt     = (const int*)  d_in[2];
    const float* tpw    = (const float*)d_in[3];
    const float* ae     = (const float*)d_in[4];
    const float* re     = (const float*)d_in[5];
    float* out = (float*)d_out;

    const int B = in_sizes[1] / NN;                  // 8
    dim3 grid(B * (NN / QPB));
    protein_enc_kernel<<<grid, BLOCK, 0, stream>>>(coords, at, rt, tpw, ae, re, out);
}